// Round 4
// baseline (129.722 us; speedup 1.0000x reference)
//
#include <hip/hip_runtime.h>

typedef float vf4 __attribute__((ext_vector_type(4)));

#define LOG2E 1.4426950408889634f
#define TWO_LOG2E 2.8853900817779268f

__device__ __forceinline__ float fexp2(float x) { return __builtin_amdgcn_exp2f(x); }
__device__ __forceinline__ float frcp(float x) { return __builtin_amdgcn_rcpf(x); }

// ---------------------------------------------------------------------------
// Kernel 1: projections. C(4096x256): rows 0..2047 = queries@Wq^T -> Qp,
// rows 2048..4095 = keyes@Wk^T -> Kp. Pre-scaled by 2*log2(e) so scores can
// feed exp2 directly (tanh(x) = 1 - 2/(exp2(2x*log2e)+1)).
__global__ __launch_bounds__(256) void proj_kernel(
    const float* __restrict__ queries, const float* __restrict__ keyes,
    const float* __restrict__ Wq, const float* __restrict__ Wk,
    float* __restrict__ Qp, float* __restrict__ Kp) {
  __shared__ alignas(16) float At[16 * 68];  // [k][m]
  __shared__ alignas(16) float Bt[16 * 68];  // [k][n]
  const int t = threadIdx.x;
  const int m0 = blockIdx.x * 64;
  const int n0 = blockIdx.y * 64;
  const bool isQ = (m0 < 2048);
  const float* X = isQ ? queries : keyes;
  const float* W = isQ ? Wq : Wk;
  float* C = isQ ? Qp : Kp;
  const int mb = isQ ? m0 : (m0 - 2048);

  const int lm = t >> 2;
  const int lq = t & 3;
  const int mm4 = (t & 15) * 4;
  const int nn4 = (t >> 4) * 4;

  float acc[4][4] = {};
  for (int kc = 0; kc < 256; kc += 16) {
    __syncthreads();
    vf4 xa = *(const vf4*)&X[(mb + lm) * 256 + kc + lq * 4];
    vf4 wb = *(const vf4*)&W[(n0 + lm) * 256 + kc + lq * 4];
#pragma unroll
    for (int c = 0; c < 4; ++c) {
      At[(lq * 4 + c) * 68 + lm] = xa[c];
      Bt[(lq * 4 + c) * 68 + lm] = wb[c];
    }
    __syncthreads();
#pragma unroll
    for (int kk = 0; kk < 16; ++kk) {
      vf4 a4 = *(const vf4*)&At[kk * 68 + mm4];
      vf4 b4 = *(const vf4*)&Bt[kk * 68 + nn4];
#pragma unroll
      for (int i = 0; i < 4; ++i)
#pragma unroll
        for (int j = 0; j < 4; ++j) acc[i][j] += a4[i] * b4[j];
    }
  }
#pragma unroll
  for (int i = 0; i < 4; ++i) {
    vf4 o = {acc[i][0] * TWO_LOG2E, acc[i][1] * TWO_LOG2E,
             acc[i][2] * TWO_LOG2E, acc[i][3] * TWO_LOG2E};
    *(vf4*)&C[(mb + mm4 + i) * 256 + n0 + nn4] = o;
  }
}

// ---------------------------------------------------------------------------
// Kernel 2 (dominant, trans-bound): full-h scores + mask + exp, no partials.
// E[b][j][i] = masked(j) ? 1 : exp(score(i,j)).  No max-subtract: |score| <=
// sum|wv| ~ 8, exp cannot overflow; masked rows (all i) would be uniform so
// E=1 reproduces softmax exactly.  Tile 32i x 32j x h=256, grid 8x8x8 = 512
// blocks (2/CU, 8 waves/CU = 2/SIMD).  Per thread 2i x 2j (halves +16).
// LDS tiles are 32-wide XOR-swizzled (colgrp ^= row&7): staging writes,
// q reads (2-way, free) and k reads (broadcast) all conflict-free.
__global__ __launch_bounds__(256) void scores_exp_kernel(
    const float* __restrict__ Qp, const float* __restrict__ Kp,
    const float* __restrict__ Wv, const int* __restrict__ valid_lens,
    float* __restrict__ E) {
  __shared__ alignas(16) float Qs[32 * 32];
  __shared__ alignas(16) float Ks[32 * 32];
  __shared__ alignas(16) float wvs[256];
  const int t = threadIdx.x;
  const int i0 = blockIdx.x * 32;
  const int j0 = blockIdx.y * 32;
  const int b = blockIdx.z;
  const int ti = t & 15;   // i = i0 + ti (+16)
  const int tj = t >> 4;   // j = j0 + tj (+16)

  // Swv = sum_h wv[h] (from global; uniform)
  float Swv;
  {
    vf4 w4 = *(const vf4*)&Wv[(t & 63) * 4];
    float sw = w4[0] + w4[1] + w4[2] + w4[3];
#pragma unroll
    for (int off = 1; off < 64; off <<= 1) sw += __shfl_xor(sw, off, 64);
    Swv = sw;
  }
  if (t < 64) *(vf4*)&wvs[t * 4] = *(const vf4*)&Wv[t * 4];

  const int srow = t >> 3;       // staging row 0..31
  const int scg = t & 7;         // staging col-group 0..7
  const int swcol = ((scg ^ (srow & 7)) << 2);
  const int qxor = ti & 7;       // (ti+16)&7 == ti&7
  const int kxor = tj & 7;

  float acc[2][2] = {};
  for (int hc = 0; hc < 8; ++hc) {
    __syncthreads();
    vf4 qv = *(const vf4*)&Qp[(((b << 8) + i0 + srow) << 8) + hc * 32 + scg * 4];
    vf4 kv = *(const vf4*)&Kp[(((b << 8) + j0 + srow) << 8) + hc * 32 + scg * 4];
    *(vf4*)&Qs[srow * 32 + swcol] = qv;
    *(vf4*)&Ks[srow * 32 + swcol] = kv;
    __syncthreads();
#pragma unroll
    for (int hh = 0; hh < 8; ++hh) {
      vf4 q0 = *(const vf4*)&Qs[ti * 32 + ((hh ^ qxor) << 2)];
      vf4 q1 = *(const vf4*)&Qs[(ti + 16) * 32 + ((hh ^ qxor) << 2)];
      vf4 k0 = *(const vf4*)&Ks[tj * 32 + ((hh ^ kxor) << 2)];
      vf4 k1 = *(const vf4*)&Ks[(tj + 16) * 32 + ((hh ^ kxor) << 2)];
      vf4 wv4 = *(const vf4*)&wvs[hc * 32 + hh * 4];
#pragma unroll
      for (int e = 0; e < 4; ++e) {
        const float we = wv4[e];
        acc[0][0] += we * frcp(fexp2(q0[e] + k0[e]) + 1.0f);
        acc[0][1] += we * frcp(fexp2(q0[e] + k1[e]) + 1.0f);
        acc[1][0] += we * frcp(fexp2(q1[e] + k0[e]) + 1.0f);
        acc[1][1] += we * frcp(fexp2(q1[e] + k1[e]) + 1.0f);
      }
    }
  }

  const int len = valid_lens[b];
#pragma unroll
  for (int c = 0; c < 2; ++c) {
    const int j = j0 + tj + 16 * c;
    const bool masked = (j >= len);
#pragma unroll
    for (int r = 0; r < 2; ++r) {
      const int i = i0 + ti + 16 * r;
      const float score = Swv - 2.0f * acc[r][c];
      const float ev = masked ? 1.0f : fexp2(score * LOG2E);
      E[(((b << 8) + j) << 8) + i] = ev;
    }
  }
}

// ---------------------------------------------------------------------------
// Kernel 3: R[b,j] = 1 / sum_i E[b,j,i].  Wave per row (2048 rows).
// Masked rows sum to exactly 256 -> uniform 1/256, matching reference.
__global__ __launch_bounds__(256) void rowsum_kernel(
    const float* __restrict__ E, float* __restrict__ R) {
  const int t = threadIdx.x;
  const int l = t & 63;
  const int row = blockIdx.x * 4 + (t >> 6);
  vf4 v = *(const vf4*)&E[(row << 8) + l * 4];
  float s = v[0] + v[1] + v[2] + v[3];
#pragma unroll
  for (int off = 1; off < 64; off <<= 1) s += __shfl_xor(s, off, 64);
  if (l == 0) R[row] = frcp(s);
}

// ---------------------------------------------------------------------------
// Kernel 4: out[b,i,d] = sum_j (E[b,j,i]*R[b,j]) * V[b,j,d].  Both operands
// j-major -> b128 outer-product staging, r[j] folded into the A-tile during
// staging.  Tile 32i x 64d, 128 threads, 4x4/thread. Grid 8x4x8 = 256 blocks.
__global__ __launch_bounds__(128) void out_kernel(
    const float* __restrict__ E, const float* __restrict__ R,
    const float* __restrict__ V, float* __restrict__ out) {
  __shared__ alignas(16) float As[32 * 36];  // [j][i]
  __shared__ alignas(16) float Bs[32 * 68];  // [j][d]
  const int t = threadIdx.x;
  const int i0 = blockIdx.x * 32;
  const int d0 = blockIdx.y * 64;
  const int b = blockIdx.z;
  const int ti = t & 7;    // i = i0 + ti*4 + r
  const int td = t >> 3;   // d = d0 + td*4 + c
  const int srow = t >> 2; // staging row 0..31
  const int scg = t & 3;

  float acc[4][4] = {};
  for (int jc = 0; jc < 8; ++jc) {
    const int jb = jc * 32;
    __syncthreads();
    const float rj = R[(b << 8) + jb + srow];
#pragma unroll
    for (int s = 0; s < 2; ++s) {
      const int col = scg * 8 + s * 4;
      vf4 a = *(const vf4*)&E[(((b << 8) + jb + srow) << 8) + i0 + col];
      *(vf4*)&As[srow * 36 + col] = a * rj;
    }
#pragma unroll
    for (int s = 0; s < 4; ++s) {
      const int col = scg * 16 + s * 4;
      *(vf4*)&Bs[srow * 68 + col] =
          *(const vf4*)&V[(((b << 8) + jb + srow) << 8) + d0 + col];
    }
    __syncthreads();
#pragma unroll
    for (int j = 0; j < 32; ++j) {
      vf4 a4 = *(const vf4*)&As[j * 36 + ti * 4];
      vf4 b4 = *(const vf4*)&Bs[j * 68 + td * 4];
#pragma unroll
      for (int r = 0; r < 4; ++r)
#pragma unroll
        for (int c = 0; c < 4; ++c) acc[r][c] += a4[r] * b4[c];
    }
  }
#pragma unroll
  for (int r = 0; r < 4; ++r) {
    vf4 o = {acc[r][0], acc[r][1], acc[r][2], acc[r][3]};
    *(vf4*)&out[(((b << 8) + i0 + ti * 4 + r) << 8) + d0 + td * 4] = o;
  }
}

// ---------------------------------------------------------------------------
extern "C" void kernel_launch(void* const* d_in, const int* in_sizes, int n_in,
                              void* d_out, int out_size, void* d_ws, size_t ws_size,
                              hipStream_t stream) {
  const float* queries = (const float*)d_in[0];
  const float* keyes = (const float*)d_in[1];
  const float* values = (const float*)d_in[2];
  const int* valid_lens = (const int*)d_in[3];
  const float* Wq = (const float*)d_in[4];
  const float* Wk = (const float*)d_in[5];
  const float* Wv = (const float*)d_in[6];
  float* out = (float*)d_out;

  float* Qp = (float*)d_ws;   // 2 MB
  float* Kp = Qp + 524288;    // 2 MB
  float* E = Kp + 524288;     // 2 MB, [b][j][i]
  float* R = E + 524288;      // 8 KB, [b][j]

  proj_kernel<<<dim3(64, 4), 256, 0, stream>>>(queries, keyes, Wq, Wk, Qp, Kp);
  scores_exp_kernel<<<dim3(8, 8, 8), 256, 0, stream>>>(Qp, Kp, Wv, valid_lens, E);
  rowsum_kernel<<<512, 256, 0, stream>>>(E, R);
  out_kernel<<<dim3(8, 4, 8), 128, 0, stream>>>(E, R, values, out);
}

// Round 5
// 125.436 us; speedup vs baseline: 1.0342x; 1.0342x over previous
//
#include <hip/hip_runtime.h>

typedef float vf4 __attribute__((ext_vector_type(4)));

#define LOG2E 1.4426950408889634f
#define TWO_LOG2E 2.8853900817779268f

__device__ __forceinline__ float fexp2(float x) { return __builtin_amdgcn_exp2f(x); }
__device__ __forceinline__ float frcp(float x) { return __builtin_amdgcn_rcpf(x); }

// ---------------------------------------------------------------------------
// Kernel 1: projections, k-split x2 for occupancy (grid 512 = 2 blocks/CU).
// Half-buffers: Qp[hz] = queries@Wq^T over k-half hz, rows 0..2047;
// Kp[hz] likewise. Scores sums the halves while staging. Pre-scaled by
// 2*log2(e) so scores feeds exp2 directly (tanh(x)=1-2/(exp2(2x*log2e)+1)).
// Block (0,0,0) also zeroes Rsum[2048] (consumed by scores' atomics).
__global__ __launch_bounds__(256) void proj_kernel(
    const float* __restrict__ queries, const float* __restrict__ keyes,
    const float* __restrict__ Wq, const float* __restrict__ Wk,
    float* __restrict__ QpH, float* __restrict__ KpH,
    float* __restrict__ Rsum) {
  __shared__ alignas(16) float At[16 * 68];  // [k][m]
  __shared__ alignas(16) float Bt[16 * 68];  // [k][n]
  const int t = threadIdx.x;
  if (blockIdx.x == 0 && blockIdx.y == 0 && blockIdx.z == 0) {
    *(vf4*)&Rsum[t * 8] = (vf4){0.f, 0.f, 0.f, 0.f};
    *(vf4*)&Rsum[t * 8 + 4] = (vf4){0.f, 0.f, 0.f, 0.f};
  }
  const int m0 = blockIdx.x * 64;
  const int n0 = blockIdx.y * 64;
  const int k0 = blockIdx.z * 128;  // k-half
  const bool isQ = (m0 < 2048);
  const float* X = isQ ? queries : keyes;
  const float* W = isQ ? Wq : Wk;
  float* C = (isQ ? QpH : KpH) + blockIdx.z * 524288;
  const int mb = isQ ? m0 : (m0 - 2048);

  const int lm = t >> 2;
  const int lq = t & 3;
  const int mm4 = (t & 15) * 4;
  const int nn4 = (t >> 4) * 4;

  float acc[4][4] = {};
  for (int kc = k0; kc < k0 + 128; kc += 16) {
    __syncthreads();
    vf4 xa = *(const vf4*)&X[(mb + lm) * 256 + kc + lq * 4];
    vf4 wb = *(const vf4*)&W[(n0 + lm) * 256 + kc + lq * 4];
#pragma unroll
    for (int c = 0; c < 4; ++c) {
      At[(lq * 4 + c) * 68 + lm] = xa[c];
      Bt[(lq * 4 + c) * 68 + lm] = wb[c];
    }
    __syncthreads();
#pragma unroll
    for (int kk = 0; kk < 16; ++kk) {
      vf4 a4 = *(const vf4*)&At[kk * 68 + mm4];
      vf4 b4 = *(const vf4*)&Bt[kk * 68 + nn4];
#pragma unroll
      for (int i = 0; i < 4; ++i)
#pragma unroll
        for (int j = 0; j < 4; ++j) acc[i][j] += a4[i] * b4[j];
    }
  }
#pragma unroll
  for (int i = 0; i < 4; ++i) {
    vf4 o = {acc[i][0] * TWO_LOG2E, acc[i][1] * TWO_LOG2E,
             acc[i][2] * TWO_LOG2E, acc[i][3] * TWO_LOG2E};
    *(vf4*)&C[(mb + mm4 + i) * 256 + n0 + nn4] = o;
  }
}

// ---------------------------------------------------------------------------
// Kernel 2 (dominant, trans-bound): full-h scores + mask + exp + fused row
// sums. E[b][j][i] = masked(j) ? 1 : exp(score); block also atomicAdds its
// 32-i partial sum for each of its 32 j into Rsum[b*256+j] (proj zeroed it).
// Masked rows accumulate exactly 256.0 -> uniform 1/256, matching reference.
// Tile 32i x 32j x h=256, grid 8x8x8 = 512 (2/CU, 8 waves/CU). Per thread
// 2i x 2j (+16 halves). XOR-swizzled 32-wide LDS tiles: conflict-free.
__global__ __launch_bounds__(256) void scores_exp_kernel(
    const float* __restrict__ QpH, const float* __restrict__ KpH,
    const float* __restrict__ Wv, const int* __restrict__ valid_lens,
    float* __restrict__ E, float* __restrict__ Rsum) {
  __shared__ alignas(16) float Qs[32 * 32];
  __shared__ alignas(16) float Ks[32 * 32];
  __shared__ alignas(16) float wvs[256];
  const int t = threadIdx.x;
  const int i0 = blockIdx.x * 32;
  const int j0 = blockIdx.y * 32;
  const int b = blockIdx.z;
  const int ti = t & 15;   // i = i0 + ti (+16)
  const int tj = t >> 4;   // j = j0 + tj (+16)

  float Swv;  // sum_h wv[h]
  {
    vf4 w4 = *(const vf4*)&Wv[(t & 63) * 4];
    float sw = w4[0] + w4[1] + w4[2] + w4[3];
#pragma unroll
    for (int off = 1; off < 64; off <<= 1) sw += __shfl_xor(sw, off, 64);
    Swv = sw;
  }
  if (t < 64) *(vf4*)&wvs[t * 4] = *(const vf4*)&Wv[t * 4];

  const int srow = t >> 3;       // staging row 0..31
  const int scg = t & 7;         // staging col-group 0..7
  const int swcol = ((scg ^ (srow & 7)) << 2);
  const int qxor = ti & 7;
  const int kxor = tj & 7;

  float acc[2][2] = {};
  for (int hc = 0; hc < 8; ++hc) {
    __syncthreads();
    const int qoff = (((b << 8) + i0 + srow) << 8) + hc * 32 + scg * 4;
    const int koff = (((b << 8) + j0 + srow) << 8) + hc * 32 + scg * 4;
    vf4 qv = *(const vf4*)&QpH[qoff];
    vf4 qv2 = *(const vf4*)&QpH[524288 + qoff];
    vf4 kv = *(const vf4*)&KpH[koff];
    vf4 kv2 = *(const vf4*)&KpH[524288 + koff];
    *(vf4*)&Qs[srow * 32 + swcol] = qv + qv2;
    *(vf4*)&Ks[srow * 32 + swcol] = kv + kv2;
    __syncthreads();
#pragma unroll
    for (int hh = 0; hh < 8; ++hh) {
      vf4 q0 = *(const vf4*)&Qs[ti * 32 + ((hh ^ qxor) << 2)];
      vf4 q1 = *(const vf4*)&Qs[(ti + 16) * 32 + ((hh ^ qxor) << 2)];
      vf4 k0 = *(const vf4*)&Ks[tj * 32 + ((hh ^ kxor) << 2)];
      vf4 k1 = *(const vf4*)&Ks[(tj + 16) * 32 + ((hh ^ kxor) << 2)];
      vf4 wv4 = *(const vf4*)&wvs[hc * 32 + hh * 4];
#pragma unroll
      for (int e = 0; e < 4; ++e) {
        const float we = wv4[e];
        acc[0][0] += we * frcp(fexp2(q0[e] + k0[e]) + 1.0f);
        acc[0][1] += we * frcp(fexp2(q0[e] + k1[e]) + 1.0f);
        acc[1][0] += we * frcp(fexp2(q1[e] + k0[e]) + 1.0f);
        acc[1][1] += we * frcp(fexp2(q1[e] + k1[e]) + 1.0f);
      }
    }
  }

  const int len = valid_lens[b];
#pragma unroll
  for (int c = 0; c < 2; ++c) {
    const int j = j0 + tj + 16 * c;
    const bool masked = (j >= len);
    float ev[2];
#pragma unroll
    for (int r = 0; r < 2; ++r) {
      const int i = i0 + ti + 16 * r;
      const float score = Swv - 2.0f * acc[r][c];
      ev[r] = masked ? 1.0f : fexp2(score * LOG2E);
      E[(((b << 8) + j) << 8) + i] = ev[r];
    }
    // fused row-sum: reduce over the block's 32 i (2 regs x 16 ti-lanes)
    float s = ev[0] + ev[1];
#pragma unroll
    for (int off = 1; off < 16; off <<= 1) s += __shfl_xor(s, off, 64);
    if (ti == 0) atomicAdd(&Rsum[(b << 8) + j], s);
  }
}

// ---------------------------------------------------------------------------
// Kernel 3: out[b,i,d] = sum_j (E[b,j,i]/Rsum[b,j]) * V[b,j,d]. Both operands
// j-major -> b128 outer-product staging; frcp(Rsum) folded into A staging.
// Tile 32i x 64d, 128 threads, 4x4/thread. Grid 8x4x8 = 256 blocks.
__global__ __launch_bounds__(128) void out_kernel(
    const float* __restrict__ E, const float* __restrict__ Rsum,
    const float* __restrict__ V, float* __restrict__ out) {
  __shared__ alignas(16) float As[32 * 36];  // [j][i]
  __shared__ alignas(16) float Bs[32 * 68];  // [j][d]
  const int t = threadIdx.x;
  const int i0 = blockIdx.x * 32;
  const int d0 = blockIdx.y * 64;
  const int b = blockIdx.z;
  const int ti = t & 7;    // i = i0 + ti*4 + r
  const int td = t >> 3;   // d = d0 + td*4 + c
  const int srow = t >> 2; // staging row 0..31
  const int scg = t & 3;

  float acc[4][4] = {};
  for (int jc = 0; jc < 8; ++jc) {
    const int jb = jc * 32;
    __syncthreads();
    const float rj = frcp(Rsum[(b << 8) + jb + srow]);
#pragma unroll
    for (int s = 0; s < 2; ++s) {
      const int col = scg * 8 + s * 4;
      vf4 a = *(const vf4*)&E[(((b << 8) + jb + srow) << 8) + i0 + col];
      *(vf4*)&As[srow * 36 + col] = a * rj;
    }
#pragma unroll
    for (int s = 0; s < 4; ++s) {
      const int col = scg * 16 + s * 4;
      *(vf4*)&Bs[srow * 68 + col] =
          *(const vf4*)&V[(((b << 8) + jb + srow) << 8) + d0 + col];
    }
    __syncthreads();
#pragma unroll
    for (int j = 0; j < 32; ++j) {
      vf4 a4 = *(const vf4*)&As[j * 36 + ti * 4];
      vf4 b4 = *(const vf4*)&Bs[j * 68 + td * 4];
#pragma unroll
      for (int r = 0; r < 4; ++r)
#pragma unroll
        for (int c = 0; c < 4; ++c) acc[r][c] += a4[r] * b4[c];
    }
  }
#pragma unroll
  for (int r = 0; r < 4; ++r) {
    vf4 o = {acc[r][0], acc[r][1], acc[r][2], acc[r][3]};
    *(vf4*)&out[(((b << 8) + i0 + ti * 4 + r) << 8) + d0 + td * 4] = o;
  }
}

// ---------------------------------------------------------------------------
extern "C" void kernel_launch(void* const* d_in, const int* in_sizes, int n_in,
                              void* d_out, int out_size, void* d_ws, size_t ws_size,
                              hipStream_t stream) {
  const float* queries = (const float*)d_in[0];
  const float* keyes = (const float*)d_in[1];
  const float* values = (const float*)d_in[2];
  const int* valid_lens = (const int*)d_in[3];
  const float* Wq = (const float*)d_in[4];
  const float* Wk = (const float*)d_in[5];
  const float* Wv = (const float*)d_in[6];
  float* out = (float*)d_out;

  float* QpH = (float*)d_ws;       // 2 x 2 MB (k-halves)
  float* KpH = QpH + 2 * 524288;   // 2 x 2 MB
  float* E = KpH + 2 * 524288;     // 2 MB, [b][j][i]
  float* Rsum = E + 524288;        // 8 KB, [b][j]

  proj_kernel<<<dim3(64, 4, 2), 256, 0, stream>>>(queries, keyes, Wq, Wk,
                                                  QpH, KpH, Rsum);
  scores_exp_kernel<<<dim3(8, 8, 8), 256, 0, stream>>>(QpH, KpH, Wv,
                                                       valid_lens, E, Rsum);
  out_kernel<<<dim3(8, 4, 8), 128, 0, stream>>>(E, Rsum, values, out);
}

// Round 6
// 111.155 us; speedup vs baseline: 1.1670x; 1.1285x over previous
//
#include <hip/hip_runtime.h>

typedef float vf4 __attribute__((ext_vector_type(4)));

#define LOG2E 1.4426950408889634f
#define TWO_LOG2E 2.8853900817779268f

__device__ __forceinline__ float fexp2(float x) { return __builtin_amdgcn_exp2f(x); }
__device__ __forceinline__ float frcp(float x) { return __builtin_amdgcn_rcpf(x); }

// ---------------------------------------------------------------------------
// Kernel 1: projections, k-split x2 (grid 512 = 2 blocks/CU), with the exp
// FOLDED INTO THE EPILOGUE: stores Ep = exp2(2*log2e * acc_half). Scores then
// needs only products: tanh(q+k) = 1 - 2/(Eq*Fk + 1), Eq = Eq1*Eq2.
// Rows 0..2047 = queries@Wq^T -> QpH, else keyes@Wk^T -> KpH.
// Block (0,0,0) also zeroes Rsum[2048] (consumed by scores' atomics).
__global__ __launch_bounds__(256) void proj_kernel(
    const float* __restrict__ queries, const float* __restrict__ keyes,
    const float* __restrict__ Wq, const float* __restrict__ Wk,
    float* __restrict__ QpH, float* __restrict__ KpH,
    float* __restrict__ Rsum) {
  __shared__ alignas(16) float At[16 * 68];  // [k][m]
  __shared__ alignas(16) float Bt[16 * 68];  // [k][n]
  const int t = threadIdx.x;
  if (blockIdx.x == 0 && blockIdx.y == 0 && blockIdx.z == 0) {
    *(vf4*)&Rsum[t * 8] = (vf4){0.f, 0.f, 0.f, 0.f};
    *(vf4*)&Rsum[t * 8 + 4] = (vf4){0.f, 0.f, 0.f, 0.f};
  }
  const int m0 = blockIdx.x * 64;
  const int n0 = blockIdx.y * 64;
  const int k0 = blockIdx.z * 128;  // k-half
  const bool isQ = (m0 < 2048);
  const float* X = isQ ? queries : keyes;
  const float* W = isQ ? Wq : Wk;
  float* C = (isQ ? QpH : KpH) + blockIdx.z * 524288;
  const int mb = isQ ? m0 : (m0 - 2048);

  const int lm = t >> 2;
  const int lq = t & 3;
  const int mm4 = (t & 15) * 4;
  const int nn4 = (t >> 4) * 4;

  float acc[4][4] = {};
  for (int kc = k0; kc < k0 + 128; kc += 16) {
    __syncthreads();
    vf4 xa = *(const vf4*)&X[(mb + lm) * 256 + kc + lq * 4];
    vf4 wb = *(const vf4*)&W[(n0 + lm) * 256 + kc + lq * 4];
#pragma unroll
    for (int c = 0; c < 4; ++c) {
      At[(lq * 4 + c) * 68 + lm] = xa[c];
      Bt[(lq * 4 + c) * 68 + lm] = wb[c];
    }
    __syncthreads();
#pragma unroll
    for (int kk = 0; kk < 16; ++kk) {
      vf4 a4 = *(const vf4*)&At[kk * 68 + mm4];
      vf4 b4 = *(const vf4*)&Bt[kk * 68 + nn4];
#pragma unroll
      for (int i = 0; i < 4; ++i)
#pragma unroll
        for (int j = 0; j < 4; ++j) acc[i][j] += a4[i] * b4[j];
    }
  }
#pragma unroll
  for (int i = 0; i < 4; ++i) {
    vf4 o = {fexp2(acc[i][0] * TWO_LOG2E), fexp2(acc[i][1] * TWO_LOG2E),
             fexp2(acc[i][2] * TWO_LOG2E), fexp2(acc[i][3] * TWO_LOG2E)};
    *(vf4*)&C[(mb + mm4 + i) * 256 + n0 + nn4] = o;
  }
}

// ---------------------------------------------------------------------------
// Kernel 2 (dominant): scores via precomputed exponentials — inner loop is
// acc += wv * rcp(Eq*Fk + 1)  (1 trans + 2 VALU per element, vs 2 trans
// before).  score = Swv - 2*acc;  E[b][j][i] = masked ? 1 : exp(score).
// Fused row sums via atomicAdd into Rsum (proj zeroed it); masked rows
// accumulate exactly 256.0 -> uniform 1/256 as the reference.
// Tile 32i x 32j x h=256, grid 8x8x8 = 512 (2 blocks/CU, 8 waves/CU).
// Per thread 2i x 2j (+16 halves).  XOR-swizzled LDS tiles: conflict-free;
// wv reads are all-lane broadcasts (free).
__global__ __launch_bounds__(256) void scores_exp_kernel(
    const float* __restrict__ QpH, const float* __restrict__ KpH,
    const float* __restrict__ Wv, const int* __restrict__ valid_lens,
    float* __restrict__ E, float* __restrict__ Rsum) {
  __shared__ alignas(16) float Qs[32 * 32];
  __shared__ alignas(16) float Ks[32 * 32];
  __shared__ alignas(16) float wvs[256];
  const int t = threadIdx.x;
  const int i0 = blockIdx.x * 32;
  const int j0 = blockIdx.y * 32;
  const int b = blockIdx.z;
  const int ti = t & 15;   // i = i0 + ti (+16)
  const int tj = t >> 4;   // j = j0 + tj (+16)

  float Swv;  // sum_h wv[h]
  {
    vf4 w4 = *(const vf4*)&Wv[(t & 63) * 4];
    float sw = w4[0] + w4[1] + w4[2] + w4[3];
#pragma unroll
    for (int off = 1; off < 64; off <<= 1) sw += __shfl_xor(sw, off, 64);
    Swv = sw;
  }
  if (t < 64) *(vf4*)&wvs[t * 4] = *(const vf4*)&Wv[t * 4];

  const int srow = t >> 3;       // staging row 0..31
  const int scg = t & 7;         // staging col-group 0..7
  const int swcol = ((scg ^ (srow & 7)) << 2);
  const int qxor = ti & 7;
  const int kxor = tj & 7;

  float acc[2][2] = {};
  for (int hc = 0; hc < 8; ++hc) {
    __syncthreads();
    const int qoff = (((b << 8) + i0 + srow) << 8) + hc * 32 + scg * 4;
    const int koff = (((b << 8) + j0 + srow) << 8) + hc * 32 + scg * 4;
    vf4 qv = *(const vf4*)&QpH[qoff];
    vf4 qv2 = *(const vf4*)&QpH[524288 + qoff];
    vf4 kv = *(const vf4*)&KpH[koff];
    vf4 kv2 = *(const vf4*)&KpH[524288 + koff];
    *(vf4*)&Qs[srow * 32 + swcol] = qv * qv2;  // product of half-exps
    *(vf4*)&Ks[srow * 32 + swcol] = kv * kv2;
    __syncthreads();
#pragma unroll
    for (int hh = 0; hh < 8; ++hh) {
      vf4 q0 = *(const vf4*)&Qs[ti * 32 + ((hh ^ qxor) << 2)];
      vf4 q1 = *(const vf4*)&Qs[(ti + 16) * 32 + ((hh ^ qxor) << 2)];
      vf4 k0 = *(const vf4*)&Ks[tj * 32 + ((hh ^ kxor) << 2)];
      vf4 k1 = *(const vf4*)&Ks[(tj + 16) * 32 + ((hh ^ kxor) << 2)];
      vf4 wv4 = *(const vf4*)&wvs[hc * 32 + hh * 4];
#pragma unroll
      for (int e = 0; e < 4; ++e) {
        const float we = wv4[e];
        acc[0][0] += we * frcp(__builtin_fmaf(q0[e], k0[e], 1.0f));
        acc[0][1] += we * frcp(__builtin_fmaf(q0[e], k1[e], 1.0f));
        acc[1][0] += we * frcp(__builtin_fmaf(q1[e], k0[e], 1.0f));
        acc[1][1] += we * frcp(__builtin_fmaf(q1[e], k1[e], 1.0f));
      }
    }
  }

  const int len = valid_lens[b];
#pragma unroll
  for (int c = 0; c < 2; ++c) {
    const int j = j0 + tj + 16 * c;
    const bool masked = (j >= len);
    float ev[2];
#pragma unroll
    for (int r = 0; r < 2; ++r) {
      const int i = i0 + ti + 16 * r;
      const float score = Swv - 2.0f * acc[r][c];
      ev[r] = masked ? 1.0f : fexp2(score * LOG2E);
      E[(((b << 8) + j) << 8) + i] = ev[r];
    }
    float s = ev[0] + ev[1];
#pragma unroll
    for (int off = 1; off < 16; off <<= 1) s += __shfl_xor(s, off, 64);
    if (ti == 0) atomicAdd(&Rsum[(b << 8) + j], s);
  }
}

// ---------------------------------------------------------------------------
// Kernel 3: out[b,i,d] = sum_j (E[b,j,i]/Rsum[b,j]) * V[b,j,d]. Both operands
// j-major -> outer-product staging; frcp(Rsum) folded into A staging.
// Tile 32i x 64d, 256 threads (2i x 4d each), grid 8x4x8 = 256 blocks
// -> 4 waves/CU (was 2).  Per j-step/thread: 2 b32 + 1 b128 LDS, 8 fma.
__global__ __launch_bounds__(256) void out_kernel(
    const float* __restrict__ E, const float* __restrict__ Rsum,
    const float* __restrict__ V, float* __restrict__ out) {
  __shared__ alignas(16) float As[32 * 36];  // [j][i]
  __shared__ alignas(16) float Bs[32 * 68];  // [j][d]
  const int t = threadIdx.x;
  const int i0 = blockIdx.x * 32;
  const int d0 = blockIdx.y * 64;
  const int b = blockIdx.z;
  const int ti = t & 15;   // i = i0 + ti (+16)
  const int td = t >> 4;   // d = d0 + td*4
  const int sr = t >> 3;   // staging row 0..31
  const int sc4 = (t & 7) * 4;

  float acc[2][4] = {};
  for (int jc = 0; jc < 8; ++jc) {
    const int jb = jc * 32;
    __syncthreads();
    const float rj = frcp(Rsum[(b << 8) + jb + sr]);
    {
      vf4 a = *(const vf4*)&E[(((b << 8) + jb + sr) << 8) + i0 + sc4];
      *(vf4*)&As[sr * 36 + sc4] = a * rj;
    }
#pragma unroll
    for (int s = 0; s < 2; ++s) {
      const int col = sc4 + s * 32;
      *(vf4*)&Bs[sr * 68 + col] =
          *(const vf4*)&V[(((b << 8) + jb + sr) << 8) + d0 + col];
    }
    __syncthreads();
#pragma unroll
    for (int j = 0; j < 32; ++j) {
      const float a0 = As[j * 36 + ti];
      const float a1 = As[j * 36 + ti + 16];
      vf4 b4 = *(const vf4*)&Bs[j * 68 + td * 4];
#pragma unroll
      for (int c = 0; c < 4; ++c) {
        acc[0][c] += a0 * b4[c];
        acc[1][c] += a1 * b4[c];
      }
    }
  }
#pragma unroll
  for (int r = 0; r < 2; ++r) {
    vf4 o = {acc[r][0], acc[r][1], acc[r][2], acc[r][3]};
    *(vf4*)&out[(((b << 8) + i0 + ti + 16 * r) << 8) + d0 + td * 4] = o;
  }
}

// ---------------------------------------------------------------------------
extern "C" void kernel_launch(void* const* d_in, const int* in_sizes, int n_in,
                              void* d_out, int out_size, void* d_ws, size_t ws_size,
                              hipStream_t stream) {
  const float* queries = (const float*)d_in[0];
  const float* keyes = (const float*)d_in[1];
  const float* values = (const float*)d_in[2];
  const int* valid_lens = (const int*)d_in[3];
  const float* Wq = (const float*)d_in[4];
  const float* Wk = (const float*)d_in[5];
  const float* Wv = (const float*)d_in[6];
  float* out = (float*)d_out;

  float* QpH = (float*)d_ws;       // 2 x 2 MB (k-half exponentials)
  float* KpH = QpH + 2 * 524288;   // 2 x 2 MB
  float* E = KpH + 2 * 524288;     // 2 MB, [b][j][i]
  float* Rsum = E + 524288;        // 8 KB, [b][j]

  proj_kernel<<<dim3(64, 4, 2), 256, 0, stream>>>(queries, keyes, Wq, Wk,
                                                  QpH, KpH, Rsum);
  scores_exp_kernel<<<dim3(8, 8, 8), 256, 0, stream>>>(QpH, KpH, Wv,
                                                       valid_lens, E, Rsum);
  out_kernel<<<dim3(8, 4, 8), 256, 0, stream>>>(E, Rsum, values, out);
}